// Round 15
// baseline (243.131 us; speedup 1.0000x reference)
//
#include <hip/hip_runtime.h>
#include <hip/hip_bf16.h>

#define NDIM  4096
#define MROWS 8192
#define PREAL 969
#define KP    1024   // 16 K-tiles of 64
#define NT    16
#define NWFOLD 1024  // wfold blocks: 16 x 64

typedef unsigned short u16;
typedef __attribute__((ext_vector_type(8))) __bf16 bf16x8;
typedef __attribute__((ext_vector_type(8))) u16 u16x8;
typedef __attribute__((ext_vector_type(4))) float f32x4;

__device__ __forceinline__ u16 bf16rne(float f) {
  unsigned int u = __builtin_bit_cast(unsigned int, f);
  u += 0x7fffu + ((u >> 16) & 1u);
  return (u16)(u >> 16);
}

// -------- compile-time multiset table: TBL.v[p] = (i<<10)|(j<<5)|k, idx 16 = "1"; -1 = pad --------
struct Tbl { int v[KP]; };
constexpr Tbl make_table() {
  Tbl t{};
  for (int p = 0; p < KP; ++p) t.v[p] = -1;
  int p = 0;
  t.v[p++] = (16 << 10) | (16 << 5) | 16;
  for (int i = 0; i < 16; ++i) t.v[p++] = (i << 10) | (16 << 5) | 16;
  for (int i = 0; i < 16; ++i)
    for (int j = i; j < 16; ++j) t.v[p++] = (i << 10) | (j << 5) | 16;
  for (int i = 0; i < 16; ++i)
    for (int j = i; j < 16; ++j)
      for (int k = j; k < 16; ++k) t.v[p++] = (i << 10) | (j << 5) | k;
  return t;
}
__device__ constexpr Tbl TBL = make_table();

// -------- merged prep (unchanged, validated): wfold + feat --------
__global__ void prep_kernel(const float* __restrict__ z, const float* __restrict__ W,
                            const float* __restrict__ bias,
                            u16* __restrict__ xb, u16* __restrict__ wfbt) {
  __shared__ float tile[64][65];
  __shared__ float zs[17];
  const int bx = blockIdx.x;
  const int tid = threadIdx.x;

  if (bx < NWFOLD) {
    const int p0 = (bx & 15) * 64;
    const int d0 = (bx >> 4) * 64;
    const int d4 = (tid & 15) * 4;
    const int rb = tid >> 4;
    const int dd = d0 + d4;
#pragma unroll
    for (int pp = 0; pp < 4; ++pp) {
      const int r = pp * 16 + rb;
      const int p = p0 + r;
      const int enc = TBL.v[p];
      f32x4 v = {0.f, 0.f, 0.f, 0.f};
      if (enc >= 0) {
        const int i = enc >> 10, j = (enc >> 5) & 31, k = enc & 31;
        if (k == 16) {
          if (j == 16) {
            if (i == 16) {
              v = *reinterpret_cast<const f32x4*>(W + dd);
              f32x4 bb = *reinterpret_cast<const f32x4*>(bias + dd);
              v.x += bb.x; v.y += bb.y; v.z += bb.z; v.w += bb.w;
            } else {
              v = *reinterpret_cast<const f32x4*>(W + (size_t)(1 + i) * NDIM + dd);
            }
          } else {
            v = *reinterpret_cast<const f32x4*>(W + (size_t)(17 + i * 16 + j) * NDIM + dd);
            if (i != j) {
              f32x4 w2 = *reinterpret_cast<const f32x4*>(W + (size_t)(17 + j * 16 + i) * NDIM + dd);
              v.x += w2.x; v.y += w2.y; v.z += w2.z; v.w += w2.w;
            }
          }
        } else {
          int rows[6];
          int nr = 0;
          rows[nr++] = 273 + i * 256 + j * 16 + k;
          if (i == j && j == k) {
          } else if (i == j) {
            rows[nr++] = 273 + i * 256 + k * 16 + i;
            rows[nr++] = 273 + k * 256 + i * 16 + i;
          } else if (j == k) {
            rows[nr++] = 273 + j * 256 + i * 16 + j;
            rows[nr++] = 273 + j * 256 + j * 16 + i;
          } else {
            rows[nr++] = 273 + i * 256 + k * 16 + j;
            rows[nr++] = 273 + j * 256 + i * 16 + k;
            rows[nr++] = 273 + j * 256 + k * 16 + i;
            rows[nr++] = 273 + k * 256 + i * 16 + j;
            rows[nr++] = 273 + k * 256 + j * 16 + i;
          }
          v = *reinterpret_cast<const f32x4*>(W + (size_t)rows[0] * NDIM + dd);
          for (int s = 1; s < nr; ++s) {
            f32x4 w2 = *reinterpret_cast<const f32x4*>(W + (size_t)rows[s] * NDIM + dd);
            v.x += w2.x; v.y += w2.y; v.z += w2.z; v.w += w2.w;
          }
        }
      }
#pragma unroll
      for (int jj = 0; jj < 4; ++jj) tile[r][d4 + jj] = v[jj];
    }
    __syncthreads();
#pragma unroll
    for (int round = 0; round < 2; ++round) {
      const int v = round * 256 + tid;
      const int d = v >> 3;
      const int tg = v & 7;
      u16x8 pack;
#pragma unroll
      for (int e = 0; e < 8; ++e) pack[e] = bf16rne(tile[tg * 8 + e][d]);
      *reinterpret_cast<u16x8*>(wfbt + (size_t)(d0 + d) * KP + p0 + tg * 8) = pack;
    }
  } else {
    const int row = bx - NWFOLD;
    if (tid < 16) zs[tid] = z[row * 16 + tid];
    if (tid == 16) zs[16] = 1.0f;
    __syncthreads();
    u16* xrow = xb + (size_t)row * KP;
    for (int g = tid; g < KP / 8; g += 256) {
      u16x8 pack;
#pragma unroll
      for (int e = 0; e < 8; ++e) {
        const int enc = TBL.v[g * 8 + e];
        float v = 0.0f;
        if (enc >= 0) v = zs[enc >> 10] * (zs[(enc >> 5) & 31] * zs[enc & 31]);
        pack[e] = bf16rne(v);
      }
      *reinterpret_cast<u16x8*>(xrow + g * 8) = pack;
    }
  }
}

// ---- 128x128 GEMM: A direct global->reg (dbuf), B LDS triple-buffer (48 KiB) -> 3 blocks/CU ----
#define GLOAD(gp, lp)                                                                     \
  __builtin_amdgcn_global_load_lds((const __attribute__((address_space(1))) unsigned int*)(gp), \
                                   (__attribute__((address_space(3))) unsigned int*)(lp), 16, 0, 0)

__device__ __forceinline__ void bar() {
  asm volatile("" ::: "memory");
  __builtin_amdgcn_s_barrier();
  asm volatile("" ::: "memory");
}

#define VM4 asm volatile("s_waitcnt vmcnt(4)" ::: "memory")
#define VM0 asm volatile("s_waitcnt vmcnt(0)" ::: "memory")

__global__ __launch_bounds__(256, 3) void gemm_kernel(const u16* __restrict__ xb,
                                                      const u16* __restrict__ wbt,
                                                      float* __restrict__ out) {
  __shared__ u16 lds[3 * 8192];  // 48 KiB: 3 x B[128][64]

  // XCD swizzle (R13-validated): 2048 blocks; window 4Mx8N fits L2
  const int bid  = blockIdx.x;
  const int xcd  = bid & 7;
  const int idx  = bid >> 3;
  const int win  = idx >> 5;
  const int w    = idx & 31;
  const int mtl  = (win >> 2) * 4 + (w >> 3);
  const int ntl  = (win & 3) * 8 + (w & 7);
  const int brow = (xcd * 8 + mtl) * 128;
  const int bcol = ntl * 128;

  const int tid  = threadIdx.x;
  const int lane = tid & 63;
  const int wid  = tid >> 6;   // 0..3
  const int wr   = wid >> 1;   // 0..1
  const int wc   = wid & 1;    // 0..1
  const int f    = lane & 15;
  const int q    = lane >> 4;
  const int f7   = f & 7;

  // B staging (R13-proven both-sides swizzle): linear LDS dest, pre-swizzled source
  const int lr = lane >> 3;
  const int swzc = ((lane & 7) ^ lr) * 8;
  const u16* gB = wbt + (size_t)(bcol + lr) * KP + swzc;
  const int sb = wid * 32;   // wave's 32-row staging group

// stage B K-tile U (4 gloads/wave = 32 rows) into buffer BUFI
#define STG_B(BUFI, U) do {                                                          \
    u16* _b = lds + (BUFI) * 8192;                                                   \
    GLOAD(gB + (size_t)(sb +  0) * KP + (U) * 64, _b + (sb +  0) * 64);              \
    GLOAD(gB + (size_t)(sb +  8) * KP + (U) * 64, _b + (sb +  8) * 64);              \
    GLOAD(gB + (size_t)(sb + 16) * KP + (U) * 64, _b + (sb + 16) * 64);              \
    GLOAD(gB + (size_t)(sb + 24) * KP + (U) * 64, _b + (sb + 24) * 64);              \
  } while (0)

  // A fragments: direct global loads (no LDS, no swizzle). lane (f,q), frag (mi,kk):
  // row = brow + wr*64 + mi*16 + f ; col = U*64 + kk*32 + q*8
  const u16* gAf = xb + (size_t)(brow + wr * 64 + f) * KP + q * 8;

#define LDA_FRAGS(DST, U) do {                                                       \
    _Pragma("unroll") for (int _m = 0; _m < 4; ++_m)                                 \
    _Pragma("unroll") for (int _k = 0; _k < 2; ++_k)                                 \
      DST[_m][_k] = *reinterpret_cast<const bf16x8*>(                                \
          gAf + (size_t)(_m * 16) * KP + (U) * 64 + _k * 32);                        \
  } while (0)

// swizzled ds_read_b128 of B fragment (R13-proven 0-conflict)
#define RD_B(ni, kk) (*reinterpret_cast<const bf16x8*>(bufB + (wc * 64 + (ni) * 16 + f) * 64 + (((kk) * 4 + q) ^ f7) * 8))

// full K-tile MFMA: 4 mi x 4 ni x 2 kk = 32
#define MFMA_TILE(ACUR) do {                                                         \
    _Pragma("unroll") for (int _i = 0; _i < 4; ++_i) {                               \
      b_[_i][0] = RD_B(_i, 0); b_[_i][1] = RD_B(_i, 1); }                            \
    __builtin_amdgcn_s_setprio(1);                                                   \
    _Pragma("unroll") for (int _m = 0; _m < 4; ++_m)                                 \
    _Pragma("unroll") for (int _n = 0; _n < 4; ++_n)                                 \
    _Pragma("unroll") for (int _k = 0; _k < 2; ++_k)                                 \
      acc[_m][_n] = __builtin_amdgcn_mfma_f32_16x16x32_bf16(                         \
          ACUR[_m][_k], b_[_n][_k], acc[_m][_n], 0, 0, 0);                           \
    __builtin_amdgcn_s_setprio(0);                                                   \
  } while (0)

// steady tile t: reads B from buf CUR with A-regs ACUR; loads A(t+1)->ANXT (8 vmem),
// stages B(t+2)->STGB (4 vmem). Entry invariant: outstanding = {B(t+1):4}.
// End fence vmcnt(4): confirms B(t+1)+A(t+1) (oldest 12), leaves B(t+2):4.
// STGB = (t+2)%3 = buffer tile t-1 read; its reads retired at t-1's barrier -> race-free.
#define TILE_STD(CUR, STGB, U2, ACUR, ANXT) do {                                     \
    const u16* bufB = lds + (CUR) * 8192;                                            \
    LDA_FRAGS(ANXT, (U2) - 1);                                                       \
    STG_B(STGB, U2);                                                                 \
    MFMA_TILE(ACUR);                                                                 \
    VM4; bar();                                                                      \
  } while (0)

  f32x4 acc[4][4] = {};
  bf16x8 aEv[4][2], aOd[4][2], b_[4][2];

  // prologue: B(0), A(0)->aEv, B(1); vmcnt(4) confirms B(0)+A(0), leaves B(1)
  STG_B(0, 0);
  LDA_FRAGS(aEv, 0);
  STG_B(1, 1);
  VM4; bar();

  // tiles 0..11: 6-tile unroll (parity 2 x buffer 3), all-static indices
  for (int t6 = 0; t6 < 12; t6 += 6) {
    TILE_STD(0, 2, t6 + 2, aEv, aOd);   // t6+0 (even)
    TILE_STD(1, 0, t6 + 3, aOd, aEv);   // t6+1 (odd)
    TILE_STD(2, 1, t6 + 4, aEv, aOd);   // t6+2
    TILE_STD(0, 2, t6 + 5, aOd, aEv);   // t6+3
    TILE_STD(1, 0, t6 + 6, aEv, aOd);   // t6+4
    TILE_STD(2, 1, t6 + 7, aOd, aEv);   // t6+5
  }
  TILE_STD(0, 2, 14, aEv, aOd);         // tile 12: stages B(14)->buf2
  TILE_STD(1, 0, 15, aOd, aEv);         // tile 13: stages B(15)->buf0
  // tile 14 (buf2, cur aEv): load A(15)->aOd, no stage; drain all
  {
    const u16* bufB = lds + 2 * 8192;
    LDA_FRAGS(aOd, 15);
    MFMA_TILE(aEv);
    VM0; bar();
  }
  // tile 15 (buf0, cur aOd): fully resident
  {
    const u16* bufB = lds;
    MFMA_TILE(aOd);
  }

  // epilogue: C/D layout col = lane&15, row = (lane>>4)*4 + j
  const int r0 = brow + wr * 64 + q * 4;
  const int c0 = bcol + wc * 64 + f;
#pragma unroll
  for (int mi = 0; mi < 4; ++mi)
#pragma unroll
    for (int ni = 0; ni < 4; ++ni) {
#pragma unroll
      for (int j = 0; j < 4; ++j)
        out[(size_t)(r0 + mi * 16 + j) * NDIM + (c0 + ni * 16)] = acc[mi][ni][j];
    }
}

// ---------------- fallback (ws too small): correct fp32 path on raw features ----------------
__global__ void fallback_kernel(const float* __restrict__ z, const float* __restrict__ W,
                                const float* __restrict__ bias, float* __restrict__ out) {
  __shared__ float feat[4369];
  const int row = blockIdx.x;
  const int tid = threadIdx.x;
  for (int t = tid; t < 4369; t += 256) {
    float v;
    if (t == 0) v = 1.0f;
    else if (t < 17) v = z[row * 16 + t - 1];
    else if (t < 273) { int u = t - 17; v = z[row * 16 + (u >> 4)] * z[row * 16 + (u & 15)]; }
    else { int u = t - 273; v = z[row * 16 + ((u >> 8) & 15)] * (z[row * 16 + ((u >> 4) & 15)] * z[row * 16 + (u & 15)]); }
    feat[t] = v;
  }
  __syncthreads();
  float acc[16];
#pragma unroll
  for (int j = 0; j < 16; ++j) acc[j] = bias[tid + 256 * j];
  for (int t = 0; t < 4369; ++t) {
    const float fv = feat[t];
    const float* wrow = W + (size_t)t * NDIM;
#pragma unroll
    for (int j = 0; j < 16; ++j) acc[j] = fmaf(fv, wrow[tid + 256 * j], acc[j]);
  }
  float* orow = out + (size_t)row * NDIM;
#pragma unroll
  for (int j = 0; j < 16; ++j) orow[tid + 256 * j] = acc[j];
}

extern "C" void kernel_launch(void* const* d_in, const int* in_sizes, int n_in,
                              void* d_out, int out_size, void* d_ws, size_t ws_size,
                              hipStream_t stream) {
  const float* z = (const float*)d_in[0];
  const float* W = (const float*)d_in[1];
  const float* b = (const float*)d_in[2];
  float* out = (float*)d_out;

  const size_t xb_elems  = (size_t)MROWS * KP;
  const size_t wbt_elems = (size_t)NDIM * KP;
  const size_t need = (xb_elems + wbt_elems) * sizeof(u16);

  if (ws_size >= need) {
    u16* xb  = (u16*)d_ws;
    u16* wbt = xb + xb_elems;
    prep_kernel<<<NWFOLD + MROWS, 256, 0, stream>>>(z, W, b, xb, wbt);
    gemm_kernel<<<(MROWS / 128) * (NDIM / 128), 256, 0, stream>>>(xb, wbt, out);
  } else {
    fallback_kernel<<<MROWS, 256, 0, stream>>>(z, W, b, out);
  }
}

// Round 16
// 102.367 us; speedup vs baseline: 2.3751x; 2.3751x over previous
//
#include <hip/hip_runtime.h>
#include <hip/hip_bf16.h>

#define NDIM  4096
#define MROWS 8192
#define PREAL 969
#define KP    1024   // 16 K-tiles of 64
#define NT    16
#define NWFOLD 1024  // wfold blocks: 16 x 64

typedef unsigned short u16;
typedef __attribute__((ext_vector_type(8))) __bf16 bf16x8;
typedef __attribute__((ext_vector_type(8))) u16 u16x8;
typedef __attribute__((ext_vector_type(4))) float f32x4;

__device__ __forceinline__ u16 bf16rne(float f) {
  unsigned int u = __builtin_bit_cast(unsigned int, f);
  u += 0x7fffu + ((u >> 16) & 1u);
  return (u16)(u >> 16);
}

// -------- compile-time multiset table: TBL.v[p] = (i<<10)|(j<<5)|k, idx 16 = "1"; -1 = pad --------
struct Tbl { int v[KP]; };
constexpr Tbl make_table() {
  Tbl t{};
  for (int p = 0; p < KP; ++p) t.v[p] = -1;
  int p = 0;
  t.v[p++] = (16 << 10) | (16 << 5) | 16;
  for (int i = 0; i < 16; ++i) t.v[p++] = (i << 10) | (16 << 5) | 16;
  for (int i = 0; i < 16; ++i)
    for (int j = i; j < 16; ++j) t.v[p++] = (i << 10) | (j << 5) | 16;
  for (int i = 0; i < 16; ++i)
    for (int j = i; j < 16; ++j)
      for (int k = j; k < 16; ++k) t.v[p++] = (i << 10) | (j << 5) | k;
  return t;
}
__device__ constexpr Tbl TBL = make_table();

// -------- merged prep: blocks [0,NWFOLD) fold W; blocks >= NWFOLD build features (2 rows/block) --------
__global__ void prep_kernel(const float* __restrict__ z, const float* __restrict__ W,
                            const float* __restrict__ bias,
                            u16* __restrict__ xb, u16* __restrict__ wfbt) {
  __shared__ float tile[64][65];
  __shared__ float zs[2][17];
  const int bx = blockIdx.x;
  const int tid = threadIdx.x;

  if (bx < NWFOLD) {
    // ---- wfold: wfbt[d][p] = bf16( sum_{t in perms(p)} W[t][d] + (p==0 ? b[d] : 0) ) ----
    const int p0 = (bx & 15) * 64;
    const int d0 = (bx >> 4) * 64;
    const int d4 = (tid & 15) * 4;
    const int rb = tid >> 4;
    const int dd = d0 + d4;
#pragma unroll
    for (int pp = 0; pp < 4; ++pp) {
      const int r = pp * 16 + rb;
      const int p = p0 + r;
      const int enc = TBL.v[p];
      f32x4 v = {0.f, 0.f, 0.f, 0.f};
      if (enc >= 0) {
        const int i = enc >> 10, j = (enc >> 5) & 31, k = enc & 31;
        if (k == 16) {
          if (j == 16) {
            if (i == 16) {
              v = *reinterpret_cast<const f32x4*>(W + dd);
              f32x4 bb = *reinterpret_cast<const f32x4*>(bias + dd);
              v.x += bb.x; v.y += bb.y; v.z += bb.z; v.w += bb.w;
            } else {
              v = *reinterpret_cast<const f32x4*>(W + (size_t)(1 + i) * NDIM + dd);
            }
          } else {
            v = *reinterpret_cast<const f32x4*>(W + (size_t)(17 + i * 16 + j) * NDIM + dd);
            if (i != j) {
              f32x4 w2 = *reinterpret_cast<const f32x4*>(W + (size_t)(17 + j * 16 + i) * NDIM + dd);
              v.x += w2.x; v.y += w2.y; v.z += w2.z; v.w += w2.w;
            }
          }
        } else {
          int rows[6];
          int nr = 0;
          rows[nr++] = 273 + i * 256 + j * 16 + k;
          if (i == j && j == k) {
          } else if (i == j) {
            rows[nr++] = 273 + i * 256 + k * 16 + i;
            rows[nr++] = 273 + k * 256 + i * 16 + i;
          } else if (j == k) {
            rows[nr++] = 273 + j * 256 + i * 16 + j;
            rows[nr++] = 273 + j * 256 + j * 16 + i;
          } else {
            rows[nr++] = 273 + i * 256 + k * 16 + j;
            rows[nr++] = 273 + j * 256 + i * 16 + k;
            rows[nr++] = 273 + j * 256 + k * 16 + i;
            rows[nr++] = 273 + k * 256 + i * 16 + j;
            rows[nr++] = 273 + k * 256 + j * 16 + i;
          }
          v = *reinterpret_cast<const f32x4*>(W + (size_t)rows[0] * NDIM + dd);
          for (int s = 1; s < nr; ++s) {
            f32x4 w2 = *reinterpret_cast<const f32x4*>(W + (size_t)rows[s] * NDIM + dd);
            v.x += w2.x; v.y += w2.y; v.z += w2.z; v.w += w2.w;
          }
        }
      }
#pragma unroll
      for (int jj = 0; jj < 4; ++jj) tile[r][d4 + jj] = v[jj];
    }
    __syncthreads();
#pragma unroll
    for (int round = 0; round < 2; ++round) {
      const int v = round * 256 + tid;
      const int d = v >> 3;
      const int tg = v & 7;
      u16x8 pack;
#pragma unroll
      for (int e = 0; e < 8; ++e) pack[e] = bf16rne(tile[tg * 8 + e][d]);
      *reinterpret_cast<u16x8*>(wfbt + (size_t)(d0 + d) * KP + p0 + tg * 8) = pack;
    }
  } else {
    // ---- feat: 2 rows per block, full-wave utilization (128 groups/row x 2 rows = 256 threads)
    const int half = tid >> 7;                 // 0..1: which row this thread serves
    const int g    = tid & 127;                // group within row
    const int row  = (bx - NWFOLD) * 2 + half;
    if (tid < 32) {
      const int h = tid >> 4, i = tid & 15;
      zs[h][i] = z[(size_t)((bx - NWFOLD) * 2 + h) * 16 + i];
    }
    if (tid < 2) zs[tid][16] = 1.0f;
    __syncthreads();
    u16* xrow = xb + (size_t)row * KP;
    u16x8 pack;
#pragma unroll
    for (int e = 0; e < 8; ++e) {
      const int enc = TBL.v[g * 8 + e];
      float v = 0.0f;
      if (enc >= 0) v = zs[half][enc >> 10] * (zs[half][(enc >> 5) & 31] * zs[half][enc & 31]);
      pack[e] = bf16rne(v);
    }
    *reinterpret_cast<u16x8*>(xrow + g * 8) = pack;
  }
}

// ------- 128x128 tile GEMM (R13, byte-identical): 64 KiB LDS -> 2 blocks/CU -------
#define GLOAD(gp, lp)                                                                     \
  __builtin_amdgcn_global_load_lds((const __attribute__((address_space(1))) unsigned int*)(gp), \
                                   (__attribute__((address_space(3))) unsigned int*)(lp), 16, 0, 0)

__device__ __forceinline__ void bar() {
  asm volatile("" ::: "memory");
  __builtin_amdgcn_s_barrier();
  asm volatile("" ::: "memory");
}

#define VM4 asm volatile("s_waitcnt vmcnt(4)" ::: "memory")
#define VM2 asm volatile("s_waitcnt vmcnt(2)" ::: "memory")
#define VM0 asm volatile("s_waitcnt vmcnt(0)" ::: "memory")

__global__ __launch_bounds__(256, 2) void gemm_kernel(const u16* __restrict__ xb,
                                                      const u16* __restrict__ wbt,
                                                      float* __restrict__ out) {
  __shared__ u16 lds[2 * 16384];  // 64 KiB: per buffer A[128][64] + B[128][64]

  // XCD swizzle: 2048 blocks; window 4Mx8N fits L2
  const int bid  = blockIdx.x;
  const int xcd  = bid & 7;
  const int idx  = bid >> 3;
  const int win  = idx >> 5;
  const int w    = idx & 31;
  const int mtl  = (win >> 2) * 4 + (w >> 3);
  const int ntl  = (win & 3) * 8 + (w & 7);
  const int brow = (xcd * 8 + mtl) * 128;
  const int bcol = ntl * 128;

  const int tid  = threadIdx.x;
  const int lane = tid & 63;
  const int wid  = tid >> 6;   // 0..3
  const int wr   = wid >> 1;   // 0..1
  const int wc   = wid & 1;    // 0..1
  const int f    = lane & 15;
  const int q    = lane >> 4;
  const int f7   = f & 7;

  // staging: pre-swizzled global source, linear LDS dest (proven pattern)
  const int lr = lane >> 3;
  const int swzc = ((lane & 7) ^ lr) * 8;
  const u16* gA = xb  + (size_t)(brow + lr) * KP + swzc;
  const u16* gB = wbt + (size_t)(bcol + lr) * KP + swzc;
  const int qB0 = (wid >> 1) * 64 + (wid & 1) * 16;  // h0 base; h1 = +32

#define STGQ(gptr, region, rb, U) do {                                               \
    GLOAD((gptr) + (size_t)(rb) * KP + (U) * 64, (region) + (rb) * 64);              \
    GLOAD((gptr) + (size_t)((rb) + 8) * KP + (U) * 64, (region) + ((rb) + 8) * 64);  \
  } while (0)

#define RD_A(mi, kk) (*reinterpret_cast<const bf16x8*>(bufA + (wr * 64 + (mi) * 16 + f) * 64 + (((kk) * 4 + q) ^ f7) * 8))
#define RD_B(ni, kk) (*reinterpret_cast<const bf16x8*>(bufB + (wc * 64 + (ni) * 16 + f) * 64 + (((kk) * 4 + q) ^ f7) * 8))

#define RDA2(i0) do {                                                                \
    a_[i0][0] = RD_A((i0), 0);     a_[i0][1] = RD_A((i0), 1);                        \
    a_[(i0)+1][0] = RD_A((i0)+1, 0); a_[(i0)+1][1] = RD_A((i0)+1, 1);                \
  } while (0)
#define RDB2(i0) do {                                                                \
    b_[i0][0] = RD_B((i0), 0);     b_[i0][1] = RD_B((i0), 1);                        \
    b_[(i0)+1][0] = RD_B((i0)+1, 0); b_[(i0)+1][1] = RD_B((i0)+1, 1);                \
  } while (0)

#define OCT(M0, N0) do {                                                             \
    __builtin_amdgcn_s_setprio(1);                                                   \
    _Pragma("unroll") for (int _m = 0; _m < 2; ++_m)                                 \
    _Pragma("unroll") for (int _n = 0; _n < 2; ++_n)                                 \
    _Pragma("unroll") for (int _k = 0; _k < 2; ++_k)                                 \
      acc[(M0) + _m][(N0) + _n] = __builtin_amdgcn_mfma_f32_16x16x32_bf16(           \
          a_[(M0) + _m][_k], b_[(N0) + _n][_k], acc[(M0) + _m][(N0) + _n], 0, 0, 0); \
    __builtin_amdgcn_s_setprio(0);                                                   \
  } while (0)

#define TILE_BODY(cA, cB, nA, nB, U) do {                                            \
    bufA = (cA); bufB = (cB);                                                        \
    RDA2(0); RDB2(0); STGQ(gA, (nA), qB0, (U));                                      \
    bar(); OCT(0, 0); VM4; bar();                                                    \
    RDB2(2);          STGQ(gB, (nB), qB0, (U));                                      \
    bar(); OCT(0, 2); VM4; bar();                                                    \
    RDA2(2);          STGQ(gB, (nB), qB0 + 32, (U));                                 \
    bar(); OCT(2, 2); bar();                                                         \
                      STGQ(gA, (nA), qB0 + 32, (U));                                 \
    bar(); OCT(2, 0); VM4; bar();                                                    \
  } while (0)

#define TILE_LAST(cA, cB) do {                                                       \
    bufA = (cA); bufB = (cB);                                                        \
    RDA2(0); RDB2(0);                                                                \
    bar(); OCT(0, 0); VM2; bar();                                                    \
    RDB2(2);                                                                         \
    bar(); OCT(0, 2); VM0; bar();                                                    \
    RDA2(2);                                                                         \
    bar(); OCT(2, 2); bar();                                                         \
    OCT(2, 0);                                                                       \
  } while (0)

  f32x4 acc[4][4] = {};
  bf16x8 a_[4][2], b_[4][2];
  const u16 *bufA, *bufB;

  u16* b0A = lds;            u16* b0B = lds + 8192;
  u16* b1A = lds + 16384;    u16* b1B = b1A + 8192;

  STGQ(gA, b0A, qB0, 0); STGQ(gB, b0B, qB0, 0);
  STGQ(gB, b0B, qB0 + 32, 0); STGQ(gA, b0A, qB0 + 32, 0);
  VM4; bar();

  for (int t = 0; t < NT - 2; t += 2) {
    TILE_BODY(b0A, b0B, b1A, b1B, t + 1);
    TILE_BODY(b1A, b1B, b0A, b0B, t + 2);
  }
  TILE_BODY(b0A, b0B, b1A, b1B, NT - 1);
  TILE_LAST(b1A, b1B);

  const int r0 = brow + wr * 64 + q * 4;
  const int c0 = bcol + wc * 64 + f;
#pragma unroll
  for (int mi = 0; mi < 4; ++mi)
#pragma unroll
    for (int ni = 0; ni < 4; ++ni) {
#pragma unroll
      for (int j = 0; j < 4; ++j)
        out[(size_t)(r0 + mi * 16 + j) * NDIM + (c0 + ni * 16)] = acc[mi][ni][j];
    }
}

// ---------------- fallback (ws too small): correct fp32 path on raw features ----------------
__global__ void fallback_kernel(const float* __restrict__ z, const float* __restrict__ W,
                                const float* __restrict__ bias, float* __restrict__ out) {
  __shared__ float feat[4369];
  const int row = blockIdx.x;
  const int tid = threadIdx.x;
  for (int t = tid; t < 4369; t += 256) {
    float v;
    if (t == 0) v = 1.0f;
    else if (t < 17) v = z[row * 16 + t - 1];
    else if (t < 273) { int u = t - 17; v = z[row * 16 + (u >> 4)] * z[row * 16 + (u & 15)]; }
    else { int u = t - 273; v = z[row * 16 + ((u >> 8) & 15)] * (z[row * 16 + ((u >> 4) & 15)] * z[row * 16 + (u & 15)]); }
    feat[t] = v;
  }
  __syncthreads();
  float acc[16];
#pragma unroll
  for (int j = 0; j < 16; ++j) acc[j] = bias[tid + 256 * j];
  for (int t = 0; t < 4369; ++t) {
    const float fv = feat[t];
    const float* wrow = W + (size_t)t * NDIM;
#pragma unroll
    for (int j = 0; j < 16; ++j) acc[j] = fmaf(fv, wrow[tid + 256 * j], acc[j]);
  }
  float* orow = out + (size_t)row * NDIM;
#pragma unroll
  for (int j = 0; j < 16; ++j) orow[tid + 256 * j] = acc[j];
}

extern "C" void kernel_launch(void* const* d_in, const int* in_sizes, int n_in,
                              void* d_out, int out_size, void* d_ws, size_t ws_size,
                              hipStream_t stream) {
  const float* z = (const float*)d_in[0];
  const float* W = (const float*)d_in[1];
  const float* b = (const float*)d_in[2];
  float* out = (float*)d_out;

  const size_t xb_elems  = (size_t)MROWS * KP;
  const size_t wbt_elems = (size_t)NDIM * KP;
  const size_t need = (xb_elems + wbt_elems) * sizeof(u16);

  if (ws_size >= need) {
    u16* xb  = (u16*)d_ws;
    u16* wbt = xb + xb_elems;
    prep_kernel<<<NWFOLD + MROWS / 2, 256, 0, stream>>>(z, W, b, xb, wbt);
    gemm_kernel<<<(MROWS / 128) * (NDIM / 128), 256, 0, stream>>>(xb, wbt, out);
  } else {
    fallback_kernel<<<MROWS, 256, 0, stream>>>(z, W, b, out);
  }
}

// Round 17
// 96.447 us; speedup vs baseline: 2.5209x; 1.0614x over previous
//
#include <hip/hip_runtime.h>
#include <hip/hip_bf16.h>

#define NDIM  4096
#define MROWS 8192
#define PREAL 969
#define KP    1024   // 16 K-tiles of 64
#define NT    16
#define NWFOLD 1024  // wfold blocks: 16 x 64

typedef unsigned short u16;
typedef __attribute__((ext_vector_type(8))) __bf16 bf16x8;
typedef __attribute__((ext_vector_type(8))) u16 u16x8;
typedef __attribute__((ext_vector_type(4))) float f32x4;

__device__ __forceinline__ u16 bf16rne(float f) {
  unsigned int u = __builtin_bit_cast(unsigned int, f);
  u += 0x7fffu + ((u >> 16) & 1u);
  return (u16)(u >> 16);
}

// -------- compile-time multiset table: TBL.v[p] = (i<<10)|(j<<5)|k, idx 16 = "1"; -1 = pad --------
struct Tbl { int v[KP]; };
constexpr Tbl make_table() {
  Tbl t{};
  for (int p = 0; p < KP; ++p) t.v[p] = -1;
  int p = 0;
  t.v[p++] = (16 << 10) | (16 << 5) | 16;
  for (int i = 0; i < 16; ++i) t.v[p++] = (i << 10) | (16 << 5) | 16;
  for (int i = 0; i < 16; ++i)
    for (int j = i; j < 16; ++j) t.v[p++] = (i << 10) | (j << 5) | 16;
  for (int i = 0; i < 16; ++i)
    for (int j = i; j < 16; ++j)
      for (int k = j; k < 16; ++k) t.v[p++] = (i << 10) | (j << 5) | k;
  return t;
}
__device__ constexpr Tbl TBL = make_table();

// ---- merged prep: blocks [0,NWFOLD) fold W; blocks >= NWFOLD build features (4 rows/block) ----
__global__ void prep_kernel(const float* __restrict__ z, const float* __restrict__ W,
                            const float* __restrict__ bias,
                            u16* __restrict__ xb, u16* __restrict__ wfbt) {
  __shared__ float tile[64][65];
  __shared__ float zs[4][17];
  const int bx = blockIdx.x;
  const int tid = threadIdx.x;

  if (bx < NWFOLD) {
    // ---- wfold: wfbt[d][p] = bf16( sum_{t in perms(p)} W[t][d] + (p==0 ? b[d] : 0) ) ----
    const int p0 = (bx & 15) * 64;
    const int d0 = (bx >> 4) * 64;
    const int d4 = (tid & 15) * 4;
    const int rb = tid >> 4;
    const int dd = d0 + d4;
#pragma unroll
    for (int pp = 0; pp < 4; ++pp) {
      const int r = pp * 16 + rb;
      const int p = p0 + r;
      const int enc = TBL.v[p];
      f32x4 v = {0.f, 0.f, 0.f, 0.f};
      if (enc >= 0) {
        const int i = enc >> 10, j = (enc >> 5) & 31, k = enc & 31;
        if (k == 16) {
          if (j == 16) {
            if (i == 16) {
              v = *reinterpret_cast<const f32x4*>(W + dd);
              f32x4 bb = *reinterpret_cast<const f32x4*>(bias + dd);
              v.x += bb.x; v.y += bb.y; v.z += bb.z; v.w += bb.w;
            } else {
              v = *reinterpret_cast<const f32x4*>(W + (size_t)(1 + i) * NDIM + dd);
            }
          } else {
            v = *reinterpret_cast<const f32x4*>(W + (size_t)(17 + i * 16 + j) * NDIM + dd);
            if (i != j) {
              f32x4 w2 = *reinterpret_cast<const f32x4*>(W + (size_t)(17 + j * 16 + i) * NDIM + dd);
              v.x += w2.x; v.y += w2.y; v.z += w2.z; v.w += w2.w;
            }
          }
        } else {
          int rows[6];
          int nr = 0;
          rows[nr++] = 273 + i * 256 + j * 16 + k;
          if (i == j && j == k) {
          } else if (i == j) {
            rows[nr++] = 273 + i * 256 + k * 16 + i;
            rows[nr++] = 273 + k * 256 + i * 16 + i;
          } else if (j == k) {
            rows[nr++] = 273 + j * 256 + i * 16 + j;
            rows[nr++] = 273 + j * 256 + j * 16 + i;
          } else {
            rows[nr++] = 273 + i * 256 + k * 16 + j;
            rows[nr++] = 273 + j * 256 + i * 16 + k;
            rows[nr++] = 273 + j * 256 + k * 16 + i;
            rows[nr++] = 273 + k * 256 + i * 16 + j;
            rows[nr++] = 273 + k * 256 + j * 16 + i;
          }
          v = *reinterpret_cast<const f32x4*>(W + (size_t)rows[0] * NDIM + dd);
          for (int s = 1; s < nr; ++s) {
            f32x4 w2 = *reinterpret_cast<const f32x4*>(W + (size_t)rows[s] * NDIM + dd);
            v.x += w2.x; v.y += w2.y; v.z += w2.z; v.w += w2.w;
          }
        }
      }
#pragma unroll
      for (int jj = 0; jj < 4; ++jj) tile[r][d4 + jj] = v[jj];
    }
    __syncthreads();
#pragma unroll
    for (int round = 0; round < 2; ++round) {
      const int v = round * 256 + tid;
      const int d = v >> 3;
      const int tg = v & 7;
      u16x8 pack;
#pragma unroll
      for (int e = 0; e < 8; ++e) pack[e] = bf16rne(tile[tg * 8 + e][d]);
      *reinterpret_cast<u16x8*>(wfbt + (size_t)(d0 + d) * KP + p0 + tg * 8) = pack;
    }
  } else {
    // ---- feat: 4 rows per block; 64 threads/row, 2 groups of 8 per thread ----
    const int rloc = tid >> 6;                 // 0..3: row within block
    const int lane = tid & 63;                 // thread within row
    const int row0 = (bx - NWFOLD) * 4;
    if (tid < 64) {
      const int h = tid >> 4, i = tid & 15;
      zs[h][i] = z[(size_t)(row0 + h) * 16 + i];
    }
    if (tid < 4) zs[tid][16] = 1.0f;
    __syncthreads();
    u16* xrow = xb + (size_t)(row0 + rloc) * KP;
#pragma unroll
    for (int half = 0; half < 2; ++half) {
      const int g = half * 64 + lane;          // group 0..127
      u16x8 pack;
#pragma unroll
      for (int e = 0; e < 8; ++e) {
        const int enc = TBL.v[g * 8 + e];
        float v = 0.0f;
        if (enc >= 0) v = zs[rloc][enc >> 10] * (zs[rloc][(enc >> 5) & 31] * zs[rloc][enc & 31]);
        pack[e] = bf16rne(v);
      }
      *reinterpret_cast<u16x8*>(xrow + g * 8) = pack;
    }
  }
}

// ------- 128x128 tile GEMM (R13, byte-identical): 64 KiB LDS -> 2 blocks/CU -------
#define GLOAD(gp, lp)                                                                     \
  __builtin_amdgcn_global_load_lds((const __attribute__((address_space(1))) unsigned int*)(gp), \
                                   (__attribute__((address_space(3))) unsigned int*)(lp), 16, 0, 0)

__device__ __forceinline__ void bar() {
  asm volatile("" ::: "memory");
  __builtin_amdgcn_s_barrier();
  asm volatile("" ::: "memory");
}

#define VM4 asm volatile("s_waitcnt vmcnt(4)" ::: "memory")
#define VM2 asm volatile("s_waitcnt vmcnt(2)" ::: "memory")
#define VM0 asm volatile("s_waitcnt vmcnt(0)" ::: "memory")

__global__ __launch_bounds__(256, 2) void gemm_kernel(const u16* __restrict__ xb,
                                                      const u16* __restrict__ wbt,
                                                      float* __restrict__ out) {
  __shared__ u16 lds[2 * 16384];  // 64 KiB: per buffer A[128][64] + B[128][64]

  // XCD swizzle: 2048 blocks; window 4Mx8N fits L2
  const int bid  = blockIdx.x;
  const int xcd  = bid & 7;
  const int idx  = bid >> 3;
  const int win  = idx >> 5;
  const int w    = idx & 31;
  const int mtl  = (win >> 2) * 4 + (w >> 3);
  const int ntl  = (win & 3) * 8 + (w & 7);
  const int brow = (xcd * 8 + mtl) * 128;
  const int bcol = ntl * 128;

  const int tid  = threadIdx.x;
  const int lane = tid & 63;
  const int wid  = tid >> 6;   // 0..3
  const int wr   = wid >> 1;   // 0..1
  const int wc   = wid & 1;    // 0..1
  const int f    = lane & 15;
  const int q    = lane >> 4;
  const int f7   = f & 7;

  // staging: pre-swizzled global source, linear LDS dest (proven pattern)
  const int lr = lane >> 3;
  const int swzc = ((lane & 7) ^ lr) * 8;
  const u16* gA = xb  + (size_t)(brow + lr) * KP + swzc;
  const u16* gB = wbt + (size_t)(bcol + lr) * KP + swzc;
  const int qB0 = (wid >> 1) * 64 + (wid & 1) * 16;  // h0 base; h1 = +32

#define STGQ(gptr, region, rb, U) do {                                               \
    GLOAD((gptr) + (size_t)(rb) * KP + (U) * 64, (region) + (rb) * 64);              \
    GLOAD((gptr) + (size_t)((rb) + 8) * KP + (U) * 64, (region) + ((rb) + 8) * 64);  \
  } while (0)

#define RD_A(mi, kk) (*reinterpret_cast<const bf16x8*>(bufA + (wr * 64 + (mi) * 16 + f) * 64 + (((kk) * 4 + q) ^ f7) * 8))
#define RD_B(ni, kk) (*reinterpret_cast<const bf16x8*>(bufB + (wc * 64 + (ni) * 16 + f) * 64 + (((kk) * 4 + q) ^ f7) * 8))

#define RDA2(i0) do {                                                                \
    a_[i0][0] = RD_A((i0), 0);     a_[i0][1] = RD_A((i0), 1);                        \
    a_[(i0)+1][0] = RD_A((i0)+1, 0); a_[(i0)+1][1] = RD_A((i0)+1, 1);                \
  } while (0)
#define RDB2(i0) do {                                                                \
    b_[i0][0] = RD_B((i0), 0);     b_[i0][1] = RD_B((i0), 1);                        \
    b_[(i0)+1][0] = RD_B((i0)+1, 0); b_[(i0)+1][1] = RD_B((i0)+1, 1);                \
  } while (0)

#define OCT(M0, N0) do {                                                             \
    __builtin_amdgcn_s_setprio(1);                                                   \
    _Pragma("unroll") for (int _m = 0; _m < 2; ++_m)                                 \
    _Pragma("unroll") for (int _n = 0; _n < 2; ++_n)                                 \
    _Pragma("unroll") for (int _k = 0; _k < 2; ++_k)                                 \
      acc[(M0) + _m][(N0) + _n] = __builtin_amdgcn_mfma_f32_16x16x32_bf16(           \
          a_[(M0) + _m][_k], b_[(N0) + _n][_k], acc[(M0) + _m][(N0) + _n], 0, 0, 0); \
    __builtin_amdgcn_s_setprio(0);                                                   \
  } while (0)

#define TILE_BODY(cA, cB, nA, nB, U) do {                                            \
    bufA = (cA); bufB = (cB);                                                        \
    RDA2(0); RDB2(0); STGQ(gA, (nA), qB0, (U));                                      \
    bar(); OCT(0, 0); VM4; bar();                                                    \
    RDB2(2);          STGQ(gB, (nB), qB0, (U));                                      \
    bar(); OCT(0, 2); VM4; bar();                                                    \
    RDA2(2);          STGQ(gB, (nB), qB0 + 32, (U));                                 \
    bar(); OCT(2, 2); bar();                                                         \
                      STGQ(gA, (nA), qB0 + 32, (U));                                 \
    bar(); OCT(2, 0); VM4; bar();                                                    \
  } while (0)

#define TILE_LAST(cA, cB) do {                                                       \
    bufA = (cA); bufB = (cB);                                                        \
    RDA2(0); RDB2(0);                                                                \
    bar(); OCT(0, 0); VM2; bar();                                                    \
    RDB2(2);                                                                         \
    bar(); OCT(0, 2); VM0; bar();                                                    \
    RDA2(2);                                                                         \
    bar(); OCT(2, 2); bar();                                                         \
    OCT(2, 0);                                                                       \
  } while (0)

  f32x4 acc[4][4] = {};
  bf16x8 a_[4][2], b_[4][2];
  const u16 *bufA, *bufB;

  u16* b0A = lds;            u16* b0B = lds + 8192;
  u16* b1A = lds + 16384;    u16* b1B = b1A + 8192;

  STGQ(gA, b0A, qB0, 0); STGQ(gB, b0B, qB0, 0);
  STGQ(gB, b0B, qB0 + 32, 0); STGQ(gA, b0A, qB0 + 32, 0);
  VM4; bar();

  for (int t = 0; t < NT - 2; t += 2) {
    TILE_BODY(b0A, b0B, b1A, b1B, t + 1);
    TILE_BODY(b1A, b1B, b0A, b0B, t + 2);
  }
  TILE_BODY(b0A, b0B, b1A, b1B, NT - 1);
  TILE_LAST(b1A, b1B);

  const int r0 = brow + wr * 64 + q * 4;
  const int c0 = bcol + wc * 64 + f;
#pragma unroll
  for (int mi = 0; mi < 4; ++mi)
#pragma unroll
    for (int ni = 0; ni < 4; ++ni) {
#pragma unroll
      for (int j = 0; j < 4; ++j)
        out[(size_t)(r0 + mi * 16 + j) * NDIM + (c0 + ni * 16)] = acc[mi][ni][j];
    }
}

// ---------------- fallback (ws too small): correct fp32 path on raw features ----------------
__global__ void fallback_kernel(const float* __restrict__ z, const float* __restrict__ W,
                                const float* __restrict__ bias, float* __restrict__ out) {
  __shared__ float feat[4369];
  const int row = blockIdx.x;
  const int tid = threadIdx.x;
  for (int t = tid; t < 4369; t += 256) {
    float v;
    if (t == 0) v = 1.0f;
    else if (t < 17) v = z[row * 16 + t - 1];
    else if (t < 273) { int u = t - 17; v = z[row * 16 + (u >> 4)] * z[row * 16 + (u & 15)]; }
    else { int u = t - 273; v = z[row * 16 + ((u >> 8) & 15)] * (z[row * 16 + ((u >> 4) & 15)] * z[row * 16 + (u & 15)]); }
    feat[t] = v;
  }
  __syncthreads();
  float acc[16];
#pragma unroll
  for (int j = 0; j < 16; ++j) acc[j] = bias[tid + 256 * j];
  for (int t = 0; t < 4369; ++t) {
    const float fv = feat[t];
    const float* wrow = W + (size_t)t * NDIM;
#pragma unroll
    for (int j = 0; j < 16; ++j) acc[j] = fmaf(fv, wrow[tid + 256 * j], acc[j]);
  }
  float* orow = out + (size_t)row * NDIM;
#pragma unroll
  for (int j = 0; j < 16; ++j) orow[tid + 256 * j] = acc[j];
}

extern "C" void kernel_launch(void* const* d_in, const int* in_sizes, int n_in,
                              void* d_out, int out_size, void* d_ws, size_t ws_size,
                              hipStream_t stream) {
  const float* z = (const float*)d_in[0];
  const float* W = (const float*)d_in[1];
  const float* b = (const float*)d_in[2];
  float* out = (float*)d_out;

  const size_t xb_elems  = (size_t)MROWS * KP;
  const size_t wbt_elems = (size_t)NDIM * KP;
  const size_t need = (xb_elems + wbt_elems) * sizeof(u16);

  if (ws_size >= need) {
    u16* xb  = (u16*)d_ws;
    u16* wbt = xb + xb_elems;
    prep_kernel<<<NWFOLD + MROWS / 4, 256, 0, stream>>>(z, W, b, xb, wbt);
    gemm_kernel<<<(MROWS / 128) * (NDIM / 128), 256, 0, stream>>>(xb, wbt, out);
  } else {
    fallback_kernel<<<MROWS, 256, 0, stream>>>(z, W, b, out);
  }
}